// Round 2
// 1130.948 us; speedup vs baseline: 1.0554x; 1.0554x over previous
//
#include <hip/hip_runtime.h>

// Problem constants
#define TT 4096
#define HH 2048
#define CI 2816        // I
#define EE 8
#define KK 2
#define TKN (TT * KK)  // 8192 assignments
#define TM 256         // M tile (256-row expert buckets)
#define MAX_MT (TKN / TM + EE)   // 40 worst-case m-tiles
#define ROWS_PAD (MAX_MT * TM)   // 10240 padded rows

typedef short short8 __attribute__((ext_vector_type(8)));
typedef float floatx4 __attribute__((ext_vector_type(4)));

#define MFMA_B16(a, b, c) __builtin_amdgcn_mfma_f32_16x16x32_bf16(a, b, c, 0, 0, 0)

__device__ __forceinline__ unsigned short f2bf(float f) {
  unsigned u = __float_as_uint(f);
  return (unsigned short)((u + 0x8000u) >> 16);
}

__device__ __forceinline__ void cvt_store8(unsigned short* dst, float4 a, float4 b) {
  short8 v;
  v[0] = (short)f2bf(a.x); v[1] = (short)f2bf(a.y);
  v[2] = (short)f2bf(a.z); v[3] = (short)f2bf(a.w);
  v[4] = (short)f2bf(b.x); v[5] = (short)f2bf(b.y);
  v[6] = (short)f2bf(b.z); v[7] = (short)f2bf(b.w);
  *(short8*)dst = v;
}

// async global->LDS, 16B per lane; lds dest = wave-uniform base + lane*16
__device__ __forceinline__ void gload_lds16(const unsigned short* g, unsigned short* l) {
  __builtin_amdgcn_global_load_lds(
      (const __attribute__((address_space(1))) unsigned int*)g,
      (__attribute__((address_space(3))) unsigned int*)l, 16, 0, 0);
}

// swizzled LDS fragment read: row stride 64B (BK=32 bf16), XOR bank swizzle
// phys_col = log_col ^ ((row&3)<<4)  (involution; mask depends only on row bits)
__device__ __forceinline__ short8 lds_frag(const unsigned short* base, int row, int quad) {
  const int off = row * 64 + ((quad * 16) ^ ((row & 3) << 4));  // bytes
  return *(const short8*)((const char*)base + off);
}

// ---------------------------------------------------------------------------
// fp32 -> bf16 bulk convert (8 elements/thread, grid-stride)
// ---------------------------------------------------------------------------
__global__ void cvt_kernel(const float* __restrict__ src, unsigned short* __restrict__ dst,
                           int n8) {
  for (int i = blockIdx.x * blockDim.x + threadIdx.x; i < n8; i += gridDim.x * blockDim.x) {
    float4 a = ((const float4*)src)[2 * i];
    float4 b = ((const float4*)src)[2 * i + 1];
    cvt_store8(dst + (size_t)i * 8, a, b);
  }
}

// ---------------------------------------------------------------------------
// bucket tokens by expert into padded TM-row regions; record inverse map
// ---------------------------------------------------------------------------
__global__ void bucket_kernel(const int* __restrict__ ids,
                              int* __restrict__ hdr, int* __restrict__ tok,
                              int* __restrict__ inv) {
  __shared__ int cnt[EE];
  __shared__ int cur[EE];
  int tid = threadIdx.x;
  if (tid < EE) cnt[tid] = 0;
  __syncthreads();
  for (int p = tid; p < TKN; p += 256) atomicAdd(&cnt[ids[p]], 1);
  for (int r = tid; r < ROWS_PAD; r += 256) tok[r] = 0;
  __syncthreads();
  if (tid == 0) {
    int rb = 0, tb = 0;
    for (int e = 0; e < EE; e++) {
      cur[e] = rb;
      int nt = (cnt[e] + TM - 1) / TM;
      for (int j = 0; j < nt; j++) hdr[1 + tb + j] = e;
      rb += nt * TM;
      tb += nt;
    }
    for (int m = tb; m < MAX_MT; m++) hdr[1 + m] = 0;
    hdr[0] = tb;
  }
  __syncthreads();
  for (int p = tid; p < TKN; p += 256) {
    int e = ids[p];
    int slot = atomicAdd(&cur[e], 1);
    tok[slot] = p / KK;
    inv[p] = slot;
  }
}

// ---------------------------------------------------------------------------
// Shared K-loop tile body for the 256x256 / BK=32 / 4-slot-ring pipeline.
// Phases: {ds_read frags; issue prefetch; s_barrier; lgkmcnt(0); MFMA x16}
// vmcnt(8) once per tile (2 tiles * 4 loads in flight), never 0 in steady state.
// ---------------------------------------------------------------------------
#define KLOOP_BODY(T_, STAGE_, WAITN_)                                                   \
  {                                                                                      \
    const int t_ = (T_);                                                                 \
    const int slot_ = t_ & 3;                                                            \
    const unsigned short* As_ = &smem[slot_][0][0];                                      \
    const unsigned short* Bs_ = &smem[slot_][1][0];                                      \
    short8 a_[8];                                                                        \
    _Pragma("unroll")                                                                    \
    for (int m_ = 0; m_ < 8; ++m_)                                                       \
      a_[m_] = lds_frag(As_, wr * 128 + m_ * 16 + lrow, quad);                           \
    short8 b0_ = lds_frag(Bs_, wc * 64 + lrow, quad);                                    \
    short8 b1_ = lds_frag(Bs_, wc * 64 + 16 + lrow, quad);                               \
    if (STAGE_) { STAGE_A(t_ + 3); }                                                     \
    __builtin_amdgcn_s_barrier();                                                        \
    asm volatile("s_waitcnt lgkmcnt(0)" ::: "memory");                                   \
    __builtin_amdgcn_sched_barrier(0);                                                   \
    __builtin_amdgcn_s_setprio(1);                                                       \
    _Pragma("unroll")                                                                    \
    for (int m_ = 0; m_ < 8; ++m_) {                                                     \
      acc[m_][0] = MFMA_B16(a_[m_], b0_, acc[m_][0]);                                    \
      acc[m_][1] = MFMA_B16(a_[m_], b1_, acc[m_][1]);                                    \
    }                                                                                    \
    __builtin_amdgcn_s_setprio(0);                                                       \
    __builtin_amdgcn_sched_barrier(0);                                                   \
    __builtin_amdgcn_s_barrier();                                                        \
    short8 b2_ = lds_frag(Bs_, wc * 64 + 32 + lrow, quad);                               \
    short8 b3_ = lds_frag(Bs_, wc * 64 + 48 + lrow, quad);                               \
    if (STAGE_) { STAGE_B(t_ + 3); }                                                     \
    __builtin_amdgcn_s_barrier();                                                        \
    asm volatile("s_waitcnt lgkmcnt(0)" ::: "memory");                                   \
    __builtin_amdgcn_sched_barrier(0);                                                   \
    __builtin_amdgcn_s_setprio(1);                                                       \
    _Pragma("unroll")                                                                    \
    for (int m_ = 0; m_ < 8; ++m_) {                                                     \
      acc[m_][2] = MFMA_B16(a_[m_], b2_, acc[m_][2]);                                    \
      acc[m_][3] = MFMA_B16(a_[m_], b3_, acc[m_][3]);                                    \
    }                                                                                    \
    __builtin_amdgcn_s_setprio(0);                                                       \
    __builtin_amdgcn_sched_barrier(0);                                                   \
    if ((WAITN_) == 8)      asm volatile("s_waitcnt vmcnt(8)" ::: "memory");             \
    else if ((WAITN_) == 4) asm volatile("s_waitcnt vmcnt(4)" ::: "memory");             \
    else if ((WAITN_) == 0) asm volatile("s_waitcnt vmcnt(0)" ::: "memory");             \
    __builtin_amdgcn_s_barrier();                                                        \
  }

// ---------------------------------------------------------------------------
// GEMM1: act tile 256 tokens x 128 act-cols; B rows = 128 gate + 128 up
// interleaved per-wave (wave wc owns 32 gate + 32 up rows for the same cols).
// ---------------------------------------------------------------------------
__global__ __launch_bounds__(512, 2)
void gemm1_kernel(const unsigned short* __restrict__ xb, const unsigned short* __restrict__ w13b,
                  const int* __restrict__ hdr, const int* __restrict__ tok,
                  unsigned short* __restrict__ act) {
  const int nwg = MAX_MT * (CI / 128);        // 880, %8==0 -> simple bijective xcd swizzle
  int orig = blockIdx.y * MAX_MT + blockIdx.x;
  int id = (orig & 7) * (nwg >> 3) + (orig >> 3);
  const int mt = id / (CI / 128);
  const int bn = id % (CI / 128);
  if (mt >= hdr[0]) return;
  const int e = hdr[1 + mt];
  const int row_base = mt * TM;

  const int tid = threadIdx.x;
  const int lane = tid & 63;
  const int wave = tid >> 6;
  const int wr = wave >> 2;   // row half 0..1
  const int wc = wave & 3;    // col group 0..3
  const int lrow = lane & 15;
  const int quad = lane >> 4;

  __shared__ __align__(16) unsigned short smem[4][2][8192];  // 4 slots x (A,B) x 256x32 bf16

  // staging setup: thread covers rows r0 (issue 0) and r0+128 (issue 1), 16B each
  const int r0 = tid >> 2;                 // 0..127
  const int cph = (tid & 3) * 16;          // physical byte col in 64B row
  const int cs = cph ^ ((r0 & 3) << 4);    // logical (source) byte col

  const char* sA0 = (const char*)(xb + (size_t)tok[row_base + r0] * HH) + cs;
  const char* sA1 = (const char*)(xb + (size_t)tok[row_base + r0 + 128] * HH) + cs;
  const char* sB0;
  const char* sB1;
  {
    int l0 = r0 & 63, g0 = r0 >> 6;
    int wrow0 = (l0 < 32) ? (bn * 128 + g0 * 32 + l0) : (CI + bn * 128 + g0 * 32 + (l0 - 32));
    sB0 = (const char*)(w13b + ((size_t)e * (2 * CI) + wrow0) * HH) + cs;
    int r1 = r0 + 128;
    int l1 = r1 & 63, g1 = r1 >> 6;
    int wrow1 = (l1 < 32) ? (bn * 128 + g1 * 32 + l1) : (CI + bn * 128 + g1 * 32 + (l1 - 32));
    sB1 = (const char*)(w13b + ((size_t)e * (2 * CI) + wrow1) * HH) + cs;
  }

  auto STAGE_A = [&](int tt) {
    int s = tt & 3;
    gload_lds16((const unsigned short*)(sA0 + (size_t)tt * 64), &smem[s][0][wave * 512]);
    gload_lds16((const unsigned short*)(sA1 + (size_t)tt * 64), &smem[s][0][4096 + wave * 512]);
  };
  auto STAGE_B = [&](int tt) {
    int s = tt & 3;
    gload_lds16((const unsigned short*)(sB0 + (size_t)tt * 64), &smem[s][1][wave * 512]);
    gload_lds16((const unsigned short*)(sB1 + (size_t)tt * 64), &smem[s][1][4096 + wave * 512]);
  };

  floatx4 acc[8][4];
#pragma unroll
  for (int m = 0; m < 8; ++m)
#pragma unroll
    for (int n = 0; n < 4; ++n) acc[m][n] = (floatx4){0.f, 0.f, 0.f, 0.f};

  // prologue: tiles 0,1,2 in flight; wait oldest 4 (tile 0) landed
  STAGE_A(0); STAGE_B(0); STAGE_A(1); STAGE_B(1); STAGE_A(2); STAGE_B(2);
  asm volatile("s_waitcnt vmcnt(8)" ::: "memory");
  __builtin_amdgcn_s_barrier();

  const int NT = HH / 32;  // 64
  for (int t = 0; t < NT - 3; ++t) KLOOP_BODY(t, 1, 8);
  KLOOP_BODY(NT - 3, 0, 4);
  KLOOP_BODY(NT - 2, 0, 0);
  KLOOP_BODY(NT - 1, 0, -1);

  // epilogue: silu(gate)*up -> bf16 act
  const int colb = bn * 128 + wc * 32;
#pragma unroll
  for (int m = 0; m < 8; ++m) {
    const int row = row_base + wr * 128 + m * 16 + quad * 4;
#pragma unroll
    for (int n = 0; n < 2; ++n) {
#pragma unroll
      for (int r = 0; r < 4; ++r) {
        float g = acc[m][n][r];
        float u = acc[m][n + 2][r];
        float s = g / (1.f + __expf(-g));
        act[(size_t)(row + r) * CI + colb + n * 16 + lrow] = f2bf(s * u);
      }
    }
  }
}

// ---------------------------------------------------------------------------
// GEMM2: y[row,h] = act_row . w2[e,h,:]  (dense per block, no indirection,
// no atomics: y indexed by slot row, combine kernel applies top-k weights)
// ---------------------------------------------------------------------------
__global__ __launch_bounds__(512, 2)
void gemm2_kernel(const unsigned short* __restrict__ act, const unsigned short* __restrict__ w2b,
                  const int* __restrict__ hdr, float* __restrict__ y) {
  const int nwg = MAX_MT * (HH / 256);        // 320, %8==0
  int orig = blockIdx.y * MAX_MT + blockIdx.x;
  int id = (orig & 7) * (nwg >> 3) + (orig >> 3);
  const int mt = id / (HH / 256);
  const int bh = id % (HH / 256);
  if (mt >= hdr[0]) return;
  const int e = hdr[1 + mt];
  const int row_base = mt * TM;
  const int h0 = bh * 256;

  const int tid = threadIdx.x;
  const int lane = tid & 63;
  const int wave = tid >> 6;
  const int wr = wave >> 2;
  const int wc = wave & 3;
  const int lrow = lane & 15;
  const int quad = lane >> 4;

  __shared__ __align__(16) unsigned short smem[4][2][8192];

  const int r0 = tid >> 2;
  const int cph = (tid & 3) * 16;
  const int cs = cph ^ ((r0 & 3) << 4);

  const char* sA0 = (const char*)(act + (size_t)(row_base + r0) * CI) + cs;
  const char* sA1 = (const char*)(act + (size_t)(row_base + r0 + 128) * CI) + cs;
  const char* sB0 = (const char*)(w2b + ((size_t)e * HH + h0 + r0) * CI) + cs;
  const char* sB1 = (const char*)(w2b + ((size_t)e * HH + h0 + r0 + 128) * CI) + cs;

  auto STAGE_A = [&](int tt) {
    int s = tt & 3;
    gload_lds16((const unsigned short*)(sA0 + (size_t)tt * 64), &smem[s][0][wave * 512]);
    gload_lds16((const unsigned short*)(sA1 + (size_t)tt * 64), &smem[s][0][4096 + wave * 512]);
  };
  auto STAGE_B = [&](int tt) {
    int s = tt & 3;
    gload_lds16((const unsigned short*)(sB0 + (size_t)tt * 64), &smem[s][1][wave * 512]);
    gload_lds16((const unsigned short*)(sB1 + (size_t)tt * 64), &smem[s][1][4096 + wave * 512]);
  };

  floatx4 acc[8][4];
#pragma unroll
  for (int m = 0; m < 8; ++m)
#pragma unroll
    for (int n = 0; n < 4; ++n) acc[m][n] = (floatx4){0.f, 0.f, 0.f, 0.f};

  STAGE_A(0); STAGE_B(0); STAGE_A(1); STAGE_B(1); STAGE_A(2); STAGE_B(2);
  asm volatile("s_waitcnt vmcnt(8)" ::: "memory");
  __builtin_amdgcn_s_barrier();

  const int NT = CI / 32;  // 88
  for (int t = 0; t < NT - 3; ++t) KLOOP_BODY(t, 1, 8);
  KLOOP_BODY(NT - 3, 0, 4);
  KLOOP_BODY(NT - 2, 0, 0);
  KLOOP_BODY(NT - 1, 0, -1);

#pragma unroll
  for (int m = 0; m < 8; ++m) {
    const int row = row_base + wr * 128 + m * 16 + quad * 4;
#pragma unroll
    for (int n = 0; n < 4; ++n) {
#pragma unroll
      for (int r = 0; r < 4; ++r) {
        y[(size_t)(row + r) * HH + h0 + wc * 64 + n * 16 + lrow] = acc[m][n][r];
      }
    }
  }
}

// ---------------------------------------------------------------------------
// combine: out[t,:] = tw[t,0]*y[slot(t,0),:] + tw[t,1]*y[slot(t,1),:]
// ---------------------------------------------------------------------------
__global__ __launch_bounds__(256)
void combine_kernel(const float* __restrict__ y, const float* __restrict__ tw,
                    const int* __restrict__ inv, float* __restrict__ out) {
  const int t = blockIdx.x;
  const int s0 = inv[2 * t], s1 = inv[2 * t + 1];
  const float w0 = tw[2 * t], w1 = tw[2 * t + 1];
  const float4* y0 = (const float4*)(y + (size_t)s0 * HH);
  const float4* y1 = (const float4*)(y + (size_t)s1 * HH);
  float4* o = (float4*)(out + (size_t)t * HH);
  for (int c = threadIdx.x; c < HH / 4; c += 256) {
    float4 a = y0[c], b = y1[c];
    float4 v;
    v.x = w0 * a.x + w1 * b.x;
    v.y = w0 * a.y + w1 * b.y;
    v.z = w0 * a.z + w1 * b.z;
    v.w = w0 * a.w + w1 * b.w;
    o[c] = v;
  }
}

extern "C" void kernel_launch(void* const* d_in, const int* in_sizes, int n_in,
                              void* d_out, int out_size, void* d_ws, size_t ws_size,
                              hipStream_t stream) {
  const float* x   = (const float*)d_in[0];
  const float* w13 = (const float*)d_in[1];
  const float* w2  = (const float*)d_in[2];
  const float* tw  = (const float*)d_in[3];
  const int*   ids = (const int*)d_in[4];
  float* out = (float*)d_out;

  // workspace layout (bytes)
  char* ws = (char*)d_ws;
  int* hdr = (int*)ws;                                   // 512 B
  int* tok = (int*)(ws + 512);                           // 40960 B
  int* inv = (int*)(ws + 41472);                         // 32768 B
  unsigned short* act  = (unsigned short*)(ws + 74240);                      // 57,671,680 B
  unsigned short* xb   = (unsigned short*)(ws + 57745920ull);                // 16,777,216 B
  unsigned short* w13b = (unsigned short*)(ws + 74523136ull);                // 184,549,376 B
  unsigned short* w2b  = (unsigned short*)(ws + 259072512ull);               // 92,274,688 B
  // y (f32, 10240x2048 = 83.9 MB) aliases w13b: w13b is dead once gemm1 ends
  float* y = (float*)(ws + 74523136ull);

  bucket_kernel<<<1, 256, 0, stream>>>(ids, hdr, tok, inv);
  cvt_kernel<<<2048, 256, 0, stream>>>(x, xb, TT * HH / 8);
  cvt_kernel<<<4096, 256, 0, stream>>>(w13, w13b, EE * 2 * CI * HH / 8);
  cvt_kernel<<<4096, 256, 0, stream>>>(w2, w2b, EE * HH * CI / 8);
  gemm1_kernel<<<dim3(MAX_MT, CI / 128), 512, 0, stream>>>(xb, w13b, hdr, tok, act);
  gemm2_kernel<<<dim3(MAX_MT, HH / 256), 512, 0, stream>>>(act, w2b, hdr, y);
  combine_kernel<<<TT, 256, 0, stream>>>(y, tw, inv, out);
}

// Round 3
// 1124.717 us; speedup vs baseline: 1.0612x; 1.0055x over previous
//
#include <hip/hip_runtime.h>

// Problem constants
#define TT 4096
#define HH 2048
#define CI 2816        // I
#define EE 8
#define KK 2
#define TKN (TT * KK)  // 8192 assignments
#define TM 256         // M tile (256-row expert buckets)
#define MAX_MT (TKN / TM + EE)   // 40 worst-case m-tiles
#define ROWS_PAD (MAX_MT * TM)   // 10240 padded rows
#define NBN1 (CI / 128)          // 22 column blocks for gemm1
#define NBN2 (HH / 256)          // 8 column blocks for gemm2

typedef short short8 __attribute__((ext_vector_type(8)));
typedef float floatx4 __attribute__((ext_vector_type(4)));

#define MFMA_B16(a, b, c) __builtin_amdgcn_mfma_f32_16x16x32_bf16(a, b, c, 0, 0, 0)

__device__ __forceinline__ unsigned short f2bf(float f) {
  unsigned u = __float_as_uint(f);
  return (unsigned short)((u + 0x8000u) >> 16);
}

__device__ __forceinline__ void cvt_store8(unsigned short* dst, float4 a, float4 b) {
  short8 v;
  v[0] = (short)f2bf(a.x); v[1] = (short)f2bf(a.y);
  v[2] = (short)f2bf(a.z); v[3] = (short)f2bf(a.w);
  v[4] = (short)f2bf(b.x); v[5] = (short)f2bf(b.y);
  v[6] = (short)f2bf(b.z); v[7] = (short)f2bf(b.w);
  *(short8*)dst = v;
}

// async global->LDS, 16B per lane; lds dest = wave-uniform base + lane*16
__device__ __forceinline__ void gload_lds16(const unsigned short* g, unsigned short* l) {
  __builtin_amdgcn_global_load_lds(
      (const __attribute__((address_space(1))) unsigned int*)g,
      (__attribute__((address_space(3))) unsigned int*)l, 16, 0, 0);
}

// swizzled LDS fragment read: row stride 64B (BK=32 bf16), XOR bank swizzle
// phys_col = log_col ^ ((row&3)<<4)  (involution; mask depends only on row bits)
__device__ __forceinline__ short8 lds_frag(const unsigned short* base, int row, int quad) {
  const int off = row * 64 + ((quad * 16) ^ ((row & 3) << 4));  // bytes
  return *(const short8*)((const char*)base + off);
}

// ---------------------------------------------------------------------------
// fp32 -> bf16 bulk convert (8 elements/thread, grid-stride)
// ---------------------------------------------------------------------------
__global__ void cvt_kernel(const float* __restrict__ src, unsigned short* __restrict__ dst,
                           int n8) {
  for (int i = blockIdx.x * blockDim.x + threadIdx.x; i < n8; i += gridDim.x * blockDim.x) {
    float4 a = ((const float4*)src)[2 * i];
    float4 b = ((const float4*)src)[2 * i + 1];
    cvt_store8(dst + (size_t)i * 8, a, b);
  }
}

// ---------------------------------------------------------------------------
// bucket tokens by expert into padded TM-row regions; record inverse map;
// zero the two work-steal counters for the GEMMs.
// ---------------------------------------------------------------------------
__global__ void bucket_kernel(const int* __restrict__ ids,
                              int* __restrict__ hdr, int* __restrict__ tok,
                              int* __restrict__ inv, int* __restrict__ ctr) {
  __shared__ int cnt[EE];
  __shared__ int cur[EE];
  int tid = threadIdx.x;
  if (tid < EE) cnt[tid] = 0;
  if (tid < 2) ctr[tid] = 0;
  __syncthreads();
  for (int p = tid; p < TKN; p += 256) atomicAdd(&cnt[ids[p]], 1);
  for (int r = tid; r < ROWS_PAD; r += 256) tok[r] = 0;
  __syncthreads();
  if (tid == 0) {
    int rb = 0, tb = 0;
    for (int e = 0; e < EE; e++) {
      cur[e] = rb;
      int nt = (cnt[e] + TM - 1) / TM;
      for (int j = 0; j < nt; j++) hdr[1 + tb + j] = e;
      rb += nt * TM;
      tb += nt;
    }
    for (int m = tb; m < MAX_MT; m++) hdr[1 + m] = 0;
    hdr[0] = tb;
  }
  __syncthreads();
  for (int p = tid; p < TKN; p += 256) {
    int e = ids[p];
    int slot = atomicAdd(&cur[e], 1);
    tok[slot] = p / KK;
    inv[p] = slot;
  }
}

// ---------------------------------------------------------------------------
// K-loop tile body: 256x256 tile, BK=32, 4-slot LDS ring, counted vmcnt.
// Balanced 2 phases (8 reads + 16 MFMA, 4 reads + 16 MFMA), ONE barrier per
// tile (end, after vmcnt). Hazards: RAW covered by per-wave vmcnt ladder +
// end barrier; WAR covered by lgkmcnt(0)-before-MFMA + end barrier.
// ---------------------------------------------------------------------------
#define KLOOP_BODY(T_, STAGE_, WAITN_)                                                   \
  {                                                                                      \
    const int t_ = (T_);                                                                 \
    const int slot_ = t_ & 3;                                                            \
    const unsigned short* As_ = &smem[slot_][0][0];                                      \
    const unsigned short* Bs_ = &smem[slot_][1][0];                                      \
    short8 b_[4];                                                                        \
    short8 a_[4];                                                                        \
    _Pragma("unroll")                                                                    \
    for (int n_ = 0; n_ < 4; ++n_)                                                       \
      b_[n_] = lds_frag(Bs_, wc * 64 + n_ * 16 + lrow, quad);                            \
    _Pragma("unroll")                                                                    \
    for (int m_ = 0; m_ < 4; ++m_)                                                       \
      a_[m_] = lds_frag(As_, wr * 128 + m_ * 16 + lrow, quad);                           \
    if (STAGE_) { STAGE_A(t_ + 3); }                                                     \
    asm volatile("s_waitcnt lgkmcnt(0)" ::: "memory");                                   \
    __builtin_amdgcn_sched_barrier(0);                                                   \
    __builtin_amdgcn_s_setprio(1);                                                       \
    _Pragma("unroll")                                                                    \
    for (int m_ = 0; m_ < 4; ++m_) {                                                     \
      acc[m_][0] = MFMA_B16(a_[m_], b_[0], acc[m_][0]);                                  \
      acc[m_][1] = MFMA_B16(a_[m_], b_[1], acc[m_][1]);                                  \
      acc[m_][2] = MFMA_B16(a_[m_], b_[2], acc[m_][2]);                                  \
      acc[m_][3] = MFMA_B16(a_[m_], b_[3], acc[m_][3]);                                  \
    }                                                                                    \
    __builtin_amdgcn_s_setprio(0);                                                       \
    __builtin_amdgcn_sched_barrier(0);                                                   \
    _Pragma("unroll")                                                                    \
    for (int m_ = 0; m_ < 4; ++m_)                                                       \
      a_[m_] = lds_frag(As_, wr * 128 + (m_ + 4) * 16 + lrow, quad);                     \
    if (STAGE_) { STAGE_B(t_ + 3); }                                                     \
    asm volatile("s_waitcnt lgkmcnt(0)" ::: "memory");                                   \
    __builtin_amdgcn_sched_barrier(0);                                                   \
    __builtin_amdgcn_s_setprio(1);                                                       \
    _Pragma("unroll")                                                                    \
    for (int m_ = 0; m_ < 4; ++m_) {                                                     \
      acc[m_ + 4][0] = MFMA_B16(a_[m_], b_[0], acc[m_ + 4][0]);                          \
      acc[m_ + 4][1] = MFMA_B16(a_[m_], b_[1], acc[m_ + 4][1]);                          \
      acc[m_ + 4][2] = MFMA_B16(a_[m_], b_[2], acc[m_ + 4][2]);                          \
      acc[m_ + 4][3] = MFMA_B16(a_[m_], b_[3], acc[m_ + 4][3]);                          \
    }                                                                                    \
    __builtin_amdgcn_s_setprio(0);                                                       \
    __builtin_amdgcn_sched_barrier(0);                                                   \
    if ((WAITN_) == 8)      asm volatile("s_waitcnt vmcnt(8)" ::: "memory");             \
    else if ((WAITN_) == 4) asm volatile("s_waitcnt vmcnt(4)" ::: "memory");             \
    else if ((WAITN_) == 0) asm volatile("s_waitcnt vmcnt(0)" ::: "memory");             \
    __builtin_amdgcn_s_barrier();                                                        \
  }

// ---------------------------------------------------------------------------
// GEMM1: act tile 256 tokens x 128 act-cols; persistent blocks + work-steal.
// ---------------------------------------------------------------------------
__global__ __launch_bounds__(512, 2)
void gemm1_kernel(const unsigned short* __restrict__ xb, const unsigned short* __restrict__ w13b,
                  const int* __restrict__ hdr, const int* __restrict__ tok,
                  unsigned short* __restrict__ act, int* __restrict__ ctr) {
  const int tid = threadIdx.x;
  const int lane = tid & 63;
  const int wave = tid >> 6;
  const int wr = wave >> 2;   // row half 0..1
  const int wc = wave & 3;    // col group 0..3
  const int lrow = lane & 15;
  const int quad = lane >> 4;

  __shared__ __align__(16) unsigned short smem[4][2][8192];  // 4 slots x (A,B) x 256x32 bf16
  __shared__ int job_s;

  const int njobs = hdr[0] * NBN1;

  // per-thread staging geometry (job-invariant)
  const int r0 = tid >> 2;                 // 0..127
  const int cph = (tid & 3) * 16;          // physical byte col in 64B row
  const int cs = cph ^ ((r0 & 3) << 4);    // logical (source) byte col

  for (;;) {
    __syncthreads();
    if (tid == 0) job_s = atomicAdd(ctr, 1);
    __syncthreads();
    const int job = job_s;
    if (job >= njobs) return;
    const int mt = job / NBN1;
    const int bn = job % NBN1;
    const int e = hdr[1 + mt];
    const int row_base = mt * TM;

    const char* sA0 = (const char*)(xb + (size_t)tok[row_base + r0] * HH) + cs;
    const char* sA1 = (const char*)(xb + (size_t)tok[row_base + r0 + 128] * HH) + cs;
    const char* sB0;
    const char* sB1;
    {
      int l0 = r0 & 63, g0 = r0 >> 6;
      int wrow0 = (l0 < 32) ? (bn * 128 + g0 * 32 + l0) : (CI + bn * 128 + g0 * 32 + (l0 - 32));
      sB0 = (const char*)(w13b + ((size_t)e * (2 * CI) + wrow0) * HH) + cs;
      int r1 = r0 + 128;
      int l1 = r1 & 63, g1 = r1 >> 6;
      int wrow1 = (l1 < 32) ? (bn * 128 + g1 * 32 + l1) : (CI + bn * 128 + g1 * 32 + (l1 - 32));
      sB1 = (const char*)(w13b + ((size_t)e * (2 * CI) + wrow1) * HH) + cs;
    }

    auto STAGE_A = [&](int tt) {
      int s = tt & 3;
      gload_lds16((const unsigned short*)(sA0 + (size_t)tt * 64), &smem[s][0][wave * 512]);
      gload_lds16((const unsigned short*)(sA1 + (size_t)tt * 64), &smem[s][0][4096 + wave * 512]);
    };
    auto STAGE_B = [&](int tt) {
      int s = tt & 3;
      gload_lds16((const unsigned short*)(sB0 + (size_t)tt * 64), &smem[s][1][wave * 512]);
      gload_lds16((const unsigned short*)(sB1 + (size_t)tt * 64), &smem[s][1][4096 + wave * 512]);
    };

    floatx4 acc[8][4];
#pragma unroll
    for (int m = 0; m < 8; ++m)
#pragma unroll
      for (int n = 0; n < 4; ++n) acc[m][n] = (floatx4){0.f, 0.f, 0.f, 0.f};

    // prologue: tiles 0,1,2 in flight; wait oldest 4 (tile 0) landed
    STAGE_A(0); STAGE_B(0); STAGE_A(1); STAGE_B(1); STAGE_A(2); STAGE_B(2);
    asm volatile("s_waitcnt vmcnt(8)" ::: "memory");
    __builtin_amdgcn_s_barrier();

    const int NT = HH / 32;  // 64
    for (int t = 0; t < NT - 3; ++t) KLOOP_BODY(t, 1, 8);
    KLOOP_BODY(NT - 3, 0, 4);
    KLOOP_BODY(NT - 2, 0, 0);
    KLOOP_BODY(NT - 1, 0, -1);

    // epilogue: silu(gate)*up -> bf16 act
    const int colb = bn * 128 + wc * 32;
#pragma unroll
    for (int m = 0; m < 8; ++m) {
      const int row = row_base + wr * 128 + m * 16 + quad * 4;
#pragma unroll
      for (int n = 0; n < 2; ++n) {
#pragma unroll
        for (int r = 0; r < 4; ++r) {
          float g = acc[m][n][r];
          float u = acc[m][n + 2][r];
          float s = g / (1.f + __expf(-g));
          act[(size_t)(row + r) * CI + colb + n * 16 + lrow] = f2bf(s * u);
        }
      }
    }
  }
}

// ---------------------------------------------------------------------------
// GEMM2: y[row,h] = act_row . w2[e,h,:]; persistent blocks + work-steal.
// Dense slot-indexed y output, no atomics; combine applies top-k weights.
// ---------------------------------------------------------------------------
__global__ __launch_bounds__(512, 2)
void gemm2_kernel(const unsigned short* __restrict__ act, const unsigned short* __restrict__ w2b,
                  const int* __restrict__ hdr, float* __restrict__ y, int* __restrict__ ctr) {
  const int tid = threadIdx.x;
  const int lane = tid & 63;
  const int wave = tid >> 6;
  const int wr = wave >> 2;
  const int wc = wave & 3;
  const int lrow = lane & 15;
  const int quad = lane >> 4;

  __shared__ __align__(16) unsigned short smem[4][2][8192];
  __shared__ int job_s;

  const int njobs = hdr[0] * NBN2;

  const int r0 = tid >> 2;
  const int cph = (tid & 3) * 16;
  const int cs = cph ^ ((r0 & 3) << 4);

  for (;;) {
    __syncthreads();
    if (tid == 0) job_s = atomicAdd(ctr, 1);
    __syncthreads();
    const int job = job_s;
    if (job >= njobs) return;
    const int mt = job / NBN2;
    const int bh = job % NBN2;
    const int e = hdr[1 + mt];
    const int row_base = mt * TM;
    const int h0 = bh * 256;

    const char* sA0 = (const char*)(act + (size_t)(row_base + r0) * CI) + cs;
    const char* sA1 = (const char*)(act + (size_t)(row_base + r0 + 128) * CI) + cs;
    const char* sB0 = (const char*)(w2b + ((size_t)e * HH + h0 + r0) * CI) + cs;
    const char* sB1 = (const char*)(w2b + ((size_t)e * HH + h0 + r0 + 128) * CI) + cs;

    auto STAGE_A = [&](int tt) {
      int s = tt & 3;
      gload_lds16((const unsigned short*)(sA0 + (size_t)tt * 64), &smem[s][0][wave * 512]);
      gload_lds16((const unsigned short*)(sA1 + (size_t)tt * 64), &smem[s][0][4096 + wave * 512]);
    };
    auto STAGE_B = [&](int tt) {
      int s = tt & 3;
      gload_lds16((const unsigned short*)(sB0 + (size_t)tt * 64), &smem[s][1][wave * 512]);
      gload_lds16((const unsigned short*)(sB1 + (size_t)tt * 64), &smem[s][1][4096 + wave * 512]);
    };

    floatx4 acc[8][4];
#pragma unroll
    for (int m = 0; m < 8; ++m)
#pragma unroll
      for (int n = 0; n < 4; ++n) acc[m][n] = (floatx4){0.f, 0.f, 0.f, 0.f};

    STAGE_A(0); STAGE_B(0); STAGE_A(1); STAGE_B(1); STAGE_A(2); STAGE_B(2);
    asm volatile("s_waitcnt vmcnt(8)" ::: "memory");
    __builtin_amdgcn_s_barrier();

    const int NT = CI / 32;  // 88
    for (int t = 0; t < NT - 3; ++t) KLOOP_BODY(t, 1, 8);
    KLOOP_BODY(NT - 3, 0, 4);
    KLOOP_BODY(NT - 2, 0, 0);
    KLOOP_BODY(NT - 1, 0, -1);

#pragma unroll
    for (int m = 0; m < 8; ++m) {
      const int row = row_base + wr * 128 + m * 16 + quad * 4;
#pragma unroll
      for (int n = 0; n < 4; ++n) {
#pragma unroll
        for (int r = 0; r < 4; ++r) {
          y[(size_t)(row + r) * HH + h0 + wc * 64 + n * 16 + lrow] = acc[m][n][r];
        }
      }
    }
  }
}

// ---------------------------------------------------------------------------
// combine: out[t,:] = tw[t,0]*y[slot(t,0),:] + tw[t,1]*y[slot(t,1),:]
// ---------------------------------------------------------------------------
__global__ __launch_bounds__(256)
void combine_kernel(const float* __restrict__ y, const float* __restrict__ tw,
                    const int* __restrict__ inv, float* __restrict__ out) {
  const int t = blockIdx.x;
  const int s0 = inv[2 * t], s1 = inv[2 * t + 1];
  const float w0 = tw[2 * t], w1 = tw[2 * t + 1];
  const float4* y0 = (const float4*)(y + (size_t)s0 * HH);
  const float4* y1 = (const float4*)(y + (size_t)s1 * HH);
  float4* o = (float4*)(out + (size_t)t * HH);
  for (int c = threadIdx.x; c < HH / 4; c += 256) {
    float4 a = y0[c], b = y1[c];
    float4 v;
    v.x = w0 * a.x + w1 * b.x;
    v.y = w0 * a.y + w1 * b.y;
    v.z = w0 * a.z + w1 * b.z;
    v.w = w0 * a.w + w1 * b.w;
    o[c] = v;
  }
}

extern "C" void kernel_launch(void* const* d_in, const int* in_sizes, int n_in,
                              void* d_out, int out_size, void* d_ws, size_t ws_size,
                              hipStream_t stream) {
  const float* x   = (const float*)d_in[0];
  const float* w13 = (const float*)d_in[1];
  const float* w2  = (const float*)d_in[2];
  const float* tw  = (const float*)d_in[3];
  const int*   ids = (const int*)d_in[4];
  float* out = (float*)d_out;

  // workspace layout (bytes)
  char* ws = (char*)d_ws;
  int* hdr = (int*)ws;                                   // 512 B
  int* tok = (int*)(ws + 512);                           // 40960 B
  int* inv = (int*)(ws + 41472);                         // 32768 B
  int* ctr = (int*)(ws + 74240);                         // 64 B (2 work-steal counters)
  unsigned short* act  = (unsigned short*)(ws + 74304);                      // 57,671,680 B
  unsigned short* xb   = (unsigned short*)(ws + 57745984ull);                // 16,777,216 B
  unsigned short* w13b = (unsigned short*)(ws + 74523200ull);                // 184,549,376 B
  unsigned short* w2b  = (unsigned short*)(ws + 259072576ull);               // 92,274,688 B
  // y (f32, 10240x2048 = 83.9 MB) aliases w13b: w13b is dead once gemm1 ends
  float* y = (float*)(ws + 74523200ull);

  bucket_kernel<<<1, 256, 0, stream>>>(ids, hdr, tok, inv, ctr);
  cvt_kernel<<<2048, 256, 0, stream>>>(x, xb, TT * HH / 8);
  cvt_kernel<<<4096, 256, 0, stream>>>(w13, w13b, EE * 2 * CI * HH / 8);
  cvt_kernel<<<4096, 256, 0, stream>>>(w2, w2b, EE * HH * CI / 8);
  gemm1_kernel<<<256, 512, 0, stream>>>(xb, w13b, hdr, tok, act, ctr);
  gemm2_kernel<<<256, 512, 0, stream>>>(act, w2b, hdr, y, ctr + 1);
  combine_kernel<<<TT, 256, 0, stream>>>(y, tw, inv, out);
}